// Round 1
// baseline (2002.911 us; speedup 1.0000x reference)
//
#include <hip/hip_runtime.h>
#include <math.h>

#define K 10
#define G1 1024   // kernel-1 grid; 1024 blocks * 4 waves = 4096 waves, ~244 rows/wave

__device__ __forceinline__ void topk_insert(float (&ts)[K], int (&ti)[K], float s, int idx) {
  // ts sorted descending; static-index unrolled bubble keeps arrays in VGPRs
  if (s > ts[K - 1]) {
    ts[K - 1] = s; ti[K - 1] = idx;
#pragma unroll
    for (int j = K - 1; j > 0; --j) {
      if (ts[j] > ts[j - 1]) {
        float fs = ts[j]; ts[j] = ts[j - 1]; ts[j - 1] = fs;
        int   fi = ti[j]; ti[j] = ti[j - 1]; ti[j - 1] = fi;
      }
    }
  }
}

__device__ __forceinline__ float dot4(float4 a, float4 b) {
  return a.x * b.x + a.y * b.y + a.z * b.z + a.w * b.w;
}

// One wave per row. 384 floats = 96 float4: lanes 0..63 load f4[lane],
// lanes 0..31 additionally load f4[64+lane]. Coalesced 1KiB + 512B per row.
__global__ __launch_bounds__(256) void k_scores(const float* __restrict__ q,
                                                const float* __restrict__ db,
                                                int n_rows,
                                                float* __restrict__ cand_s,
                                                int* __restrict__ cand_i) {
  __shared__ float s_s[4 * K];
  __shared__ int   s_i[4 * K];

  const int lane = threadIdx.x & 63;
  const int wv   = threadIdx.x >> 6;
  const int wid  = blockIdx.x * 4 + wv;
  const int nw   = gridDim.x * 4;

  const float4* q4 = reinterpret_cast<const float4*>(q);
  float4 qa = q4[lane];
  float4 qb = make_float4(0.f, 0.f, 0.f, 0.f);
  if (lane < 32) qb = q4[64 + lane];

  // ||q||^2 via wave butterfly (all lanes end with the total)
  float qs = dot4(qa, qa) + dot4(qb, qb);
#pragma unroll
  for (int off = 32; off; off >>= 1) qs += __shfl_xor(qs, off);
  const float inv_qn = 1.0f / sqrtf(qs);

  float ts[K]; int ti[K];
#pragma unroll
  for (int j = 0; j < K; ++j) { ts[j] = -INFINITY; ti[j] = 0; }

  for (int r = wid; r < n_rows; r += nw) {
    const float4* p = reinterpret_cast<const float4*>(db + (size_t)r * 384);
    float4 a = p[lane];
    float dot = dot4(a, qa);
    float nrm = dot4(a, a);
    if (lane < 32) {
      float4 b = p[64 + lane];
      dot += dot4(b, qb);
      nrm += dot4(b, b);
    }
#pragma unroll
    for (int off = 32; off; off >>= 1) {
      dot += __shfl_xor(dot, off);
      nrm += __shfl_xor(nrm, off);
    }
    // score = (e.q) / (max(||e||,eps) * ||q||)  -- matches reference
    float sc = dot * inv_qn / fmaxf(sqrtf(nrm), 1e-12f);
    topk_insert(ts, ti, sc, r);   // wave-uniform branch: sc identical on all lanes
  }

  if (lane == 0) {
#pragma unroll
    for (int j = 0; j < K; ++j) { s_s[wv * K + j] = ts[j]; s_i[wv * K + j] = ti[j]; }
  }
  __syncthreads();

  if (threadIdx.x == 0) {
    // thread 0 already holds wave 0's list; fold in waves 1..3
    for (int w = 1; w < 4; ++w) {
#pragma unroll
      for (int j = 0; j < K; ++j) topk_insert(ts, ti, s_s[w * K + j], s_i[w * K + j]);
    }
#pragma unroll
    for (int j = 0; j < K; ++j) {
      cand_s[blockIdx.x * K + j] = ts[j];
      cand_i[blockIdx.x * K + j] = ti[j];
    }
  }
}

// Single block: reduce n_cand candidates to the global top-10.
__global__ __launch_bounds__(256) void k_reduce(const float* __restrict__ cand_s,
                                                const int* __restrict__ cand_i,
                                                int n_cand,
                                                float* __restrict__ out) {
  __shared__ float s_s[256 * K];   // 10 KiB
  __shared__ int   s_i[256 * K];   // 10 KiB
  const int t = threadIdx.x;

  float ts[K]; int ti[K];
#pragma unroll
  for (int j = 0; j < K; ++j) { ts[j] = -INFINITY; ti[j] = 0; }

  for (int c = t; c < n_cand; c += 256) topk_insert(ts, ti, cand_s[c], cand_i[c]);

#pragma unroll
  for (int j = 0; j < K; ++j) { s_s[t * K + j] = ts[j]; s_i[t * K + j] = ti[j]; }
  __syncthreads();

  for (int half = 128; half >= 1; half >>= 1) {
    if (t < half) {
#pragma unroll
      for (int j = 0; j < K; ++j) topk_insert(ts, ti, s_s[(t + half) * K + j], s_i[(t + half) * K + j]);
#pragma unroll
      for (int j = 0; j < K; ++j) { s_s[t * K + j] = ts[j]; s_i[t * K + j] = ti[j]; }
    }
    __syncthreads();
  }

  if (t == 0) {
#pragma unroll
    for (int j = 0; j < K; ++j) {
      out[j]     = ts[j];            // top scores (float32)
      out[K + j] = (float)ti[j];     // indices, written as float (exact < 2^24)
    }
  }
}

extern "C" void kernel_launch(void* const* d_in, const int* in_sizes, int n_in,
                              void* d_out, int out_size, void* d_ws, size_t ws_size,
                              hipStream_t stream) {
  const float* q  = (const float*)d_in[0];
  const float* db = (const float*)d_in[1];
  const int n_rows = in_sizes[1] / 384;

  // workspace: G1*K floats + G1*K ints = 80 KiB (shrink grid if ws is tiny)
  int g = G1;
  const size_t need_per_block = (size_t)K * (sizeof(float) + sizeof(int));
  if (ws_size < (size_t)g * need_per_block) {
    g = (int)(ws_size / need_per_block);
    if (g < 1) g = 1;
  }
  float* cand_s = (float*)d_ws;
  int*   cand_i = (int*)((char*)d_ws + (size_t)g * K * sizeof(float));

  k_scores<<<g, 256, 0, stream>>>(q, db, n_rows, cand_s, cand_i);
  k_reduce<<<1, 256, 0, stream>>>(cand_s, cand_i, g * K, (float*)d_out);
}